// Round 6
// baseline (94.323 us; speedup 1.0000x reference)
//
#include <hip/hip_runtime.h>

// Problem constants (B,T,H,D,M) = (2, 2048, 8, 64, 64), fp32 in/out.
#define BB 2
#define TT 2048
#define HH 8
#define DD 64
#define CC 256           // chunks over T
#define TC (TT / CC)     // 8 timesteps per chunk (= 4 segs x 2 iters)
#define STRIDE (HH * DD) // 512 floats between consecutive timesteps
#define NBH (BB * HH)    // 16
#define CPW (CC / 16)    // 16 chunks per wave in the fused scan kernel

__device__ __forceinline__ float feat(float x) {
    // elu(x) + 1 = x+1 (x>0) else exp(x)
    return x > 0.f ? x + 1.f : __expf(x);
}

__device__ __forceinline__ void feat4(float4& a) {
    a.x = feat(a.x); a.y = feat(a.y); a.z = feat(a.z); a.w = feat(a.w);
}

// Sum the 4 seg groups' values into every lane (butterfly over lanes ^16, ^32).
__device__ __forceinline__ void xorred4(float4& a) {
    a.x += __shfl_xor(a.x, 16, 64); a.y += __shfl_xor(a.y, 16, 64);
    a.z += __shfl_xor(a.z, 16, 64); a.w += __shfl_xor(a.w, 16, 64);
    a.x += __shfl_xor(a.x, 32, 64); a.y += __shfl_xor(a.y, 32, 64);
    a.z += __shfl_xor(a.z, 32, 64); a.w += __shfl_xor(a.w, 32, 64);
}

// Lane map: g = lane&15 -> d-group (d = 4g..4g+3), seg = lane>>4 -> timestep
// within group-of-4. One wave float4-load = 4 timesteps x 64 d = 1 KB.

// Kernel 1 (fused chunk-sums + exclusive prefix): one block per (b,h), 16
// waves. Wave w owns chunks w*16..w*16+15: accumulates feat(k) chunk sums,
// keeps exclusive prefixes in registers, exchanges wave totals via LDS, and
// writes the global EXCLUSIVE prefix per chunk to ws. Replaces the separate
// chunk_sums + prefix kernels (one launch boundary fewer).
__global__ void __launch_bounds__(1024)
scan_kernel(const float* __restrict__ k, float* __restrict__ ws) {
    const int bh   = blockIdx.x;              // 0..15
    const int w    = threadIdx.x >> 6;        // wave id 0..15
    const int lane = threadIdx.x & 63;
    const int g    = lane & 15;
    const int seg  = lane >> 4;

    const int b = bh >> 3, h = bh & 7;
    // first timestep of this wave's first chunk
    const size_t base = (((size_t)b * TT + w * CPW * TC + seg) * HH + h) * DD + g * 4;

    float4 excl[CPW];
    float4 run = make_float4(0.f, 0.f, 0.f, 0.f);
    #pragma unroll 4
    for (int i = 0; i < CPW; ++i) {
        const size_t o0 = base + (size_t)(i * TC) * STRIDE;
        float4 a = *(const float4*)(k + o0);
        float4 c = *(const float4*)(k + o0 + (size_t)4 * STRIDE);
        float4 s;
        s.x = feat(a.x) + feat(c.x);
        s.y = feat(a.y) + feat(c.y);
        s.z = feat(a.z) + feat(c.z);
        s.w = feat(a.w) + feat(c.w);
        xorred4(s);              // all lanes hold chunk sum for their d-quad
        excl[i] = run;
        run.x += s.x; run.y += s.y; run.z += s.z; run.w += s.w;
    }

    // exchange wave totals (per d) via LDS
    __shared__ float tot[16][DD];
    if (seg == 0)
        *(float4*)(&tot[w][g * 4]) = run;
    __syncthreads();

    float4 carry = make_float4(0.f, 0.f, 0.f, 0.f);
    for (int w2 = 0; w2 < w; ++w2) {
        const float4 t = *(const float4*)(&tot[w2][g * 4]);
        carry.x += t.x; carry.y += t.y; carry.z += t.z; carry.w += t.w;
    }

    if (seg == 0) {
        float* wsb = ws + ((size_t)bh * CC + w * CPW) * DD + g * 4;
        #pragma unroll
        for (int i = 0; i < CPW; ++i) {
            float4 e;
            e.x = excl[i].x + carry.x; e.y = excl[i].y + carry.y;
            e.z = excl[i].z + carry.z; e.w = excl[i].w + carry.w;
            *(float4*)(wsb + (size_t)i * DD) = e;
        }
    }
}

// Kernel 2: main (identical to the verified round-0 kernel). One wave per
// (b,h,c) chunk; carry is a single float4 load of the exclusive prefix.
__global__ void __launch_bounds__(64)
linattn_kernel(const float* __restrict__ q, const float* __restrict__ k,
               const float* __restrict__ v, const float* __restrict__ ws,
               float* __restrict__ out) {
    const int idx  = blockIdx.x;
    const int c    = idx & (CC - 1);
    const int h    = (idx >> 8) & (HH - 1);
    const int b    = idx >> 11;
    const int lane = threadIdx.x;
    const int g    = lane & 15;
    const int seg  = lane >> 4;

    // lane's timesteps: t0 = c*TC + seg (iter 0), t0+4 (iter 1); d = 4g..4g+3
    const size_t off0 = (((size_t)b * TT + c * TC + seg) * HH + h) * DD + g * 4;
    const size_t off1 = off0 + (size_t)4 * STRIDE;

    float4 kf0 = *(const float4*)(k + off0);
    float4 kf1 = *(const float4*)(k + off1);
    float4 qf0 = *(const float4*)(q + off0);
    float4 qf1 = *(const float4*)(q + off1);
    const float4 vv0 = *(const float4*)(v + off0);
    const float4 vv1 = *(const float4*)(v + off1);
    const float4 carry = *(const float4*)(ws + (size_t)idx * DD + g * 4);

    feat4(kf0); feat4(kf1); feat4(qf0); feat4(qf1);

    // ---- time cumsum per d: seg-inclusive scans of kf0/kf1 (Hillis-Steele o=16,32)
    float4 i0 = kf0, i1 = kf1;
    {
        float u;
        u = __shfl_up(i0.x, 16, 64); if (seg >= 1) i0.x += u;
        u = __shfl_up(i0.y, 16, 64); if (seg >= 1) i0.y += u;
        u = __shfl_up(i0.z, 16, 64); if (seg >= 1) i0.z += u;
        u = __shfl_up(i0.w, 16, 64); if (seg >= 1) i0.w += u;
        u = __shfl_up(i1.x, 16, 64); if (seg >= 1) i1.x += u;
        u = __shfl_up(i1.y, 16, 64); if (seg >= 1) i1.y += u;
        u = __shfl_up(i1.z, 16, 64); if (seg >= 1) i1.z += u;
        u = __shfl_up(i1.w, 16, 64); if (seg >= 1) i1.w += u;
        u = __shfl_up(i0.x, 32, 64); if (seg >= 2) i0.x += u;
        u = __shfl_up(i0.y, 32, 64); if (seg >= 2) i0.y += u;
        u = __shfl_up(i0.z, 32, 64); if (seg >= 2) i0.z += u;
        u = __shfl_up(i0.w, 32, 64); if (seg >= 2) i0.w += u;
        u = __shfl_up(i1.x, 32, 64); if (seg >= 2) i1.x += u;
        u = __shfl_up(i1.y, 32, 64); if (seg >= 2) i1.y += u;
        u = __shfl_up(i1.z, 32, 64); if (seg >= 2) i1.z += u;
        u = __shfl_up(i1.w, 32, 64); if (seg >= 2) i1.w += u;
    }
    // S0[d] = chunk-first-half total = i0 at seg=3 (lane 48+g), broadcast
    float4 S0;
    S0.x = __shfl(i0.x, 48 + g, 64);
    S0.y = __shfl(i0.y, 48 + g, 64);
    S0.z = __shfl(i0.z, 48 + g, 64);
    S0.w = __shfl(i0.w, 48 + g, 64);

    float4 run0, run1;   // inclusive time-cumsum of feat(k) per d
    run0.x = carry.x + i0.x; run0.y = carry.y + i0.y;
    run0.z = carry.z + i0.z; run0.w = carry.w + i0.w;
    run1.x = carry.x + S0.x + i1.x; run1.y = carry.y + S0.y + i1.y;
    run1.z = carry.z + S0.z + i1.z; run1.w = carry.w + S0.w + i1.w;

    // ---- d-prefix (inclusive over d) per timestep: in-lane prefix + group scan
    float4 p0, p1;
    p0.x = kf0.x; p0.y = p0.x + kf0.y; p0.z = p0.y + kf0.z; p0.w = p0.z + kf0.w;
    p1.x = kf1.x; p1.y = p1.x + kf1.y; p1.z = p1.y + kf1.z; p1.w = p1.z + kf1.w;
    float c0 = p0.w, c1 = p1.w;
    #pragma unroll
    for (int o = 1; o <= 8; o <<= 1) {
        float u0 = __shfl_up(c0, o, 16);
        float u1 = __shfl_up(c1, o, 16);
        if (g >= o) { c0 += u0; c1 += u1; }
    }
    const float e0 = c0 - p0.w;   // exclusive d-prefix entering this lane
    const float e1 = c1 - p1.w;

    // ---- reductions over d: s1 = qf.(d-prefix), s2 = qf.run (per timestep)
    const float sq0 = qf0.x + qf0.y + qf0.z + qf0.w;
    const float sq1 = qf1.x + qf1.y + qf1.z + qf1.w;
    float s1_0 = qf0.x * p0.x + qf0.y * p0.y + qf0.z * p0.z + qf0.w * p0.w + e0 * sq0;
    float s2_0 = qf0.x * run0.x + qf0.y * run0.y + qf0.z * run0.z + qf0.w * run0.w;
    float s1_1 = qf1.x * p1.x + qf1.y * p1.y + qf1.z * p1.z + qf1.w * p1.w + e1 * sq1;
    float s2_1 = qf1.x * run1.x + qf1.y * run1.y + qf1.z * run1.z + qf1.w * run1.w;
    #pragma unroll
    for (int o = 1; o <= 8; o <<= 1) {
        s1_0 += __shfl_xor(s1_0, o, 64);
        s2_0 += __shfl_xor(s2_0, o, 64);
        s1_1 += __shfl_xor(s1_1, o, 64);
        s2_1 += __shfl_xor(s2_1, o, 64);
    }

    const float r0 = s1_0 * __builtin_amdgcn_rcpf(s2_0);
    const float r1 = s1_1 * __builtin_amdgcn_rcpf(s2_1);
    float4 o0, o1;
    o0.x = vv0.x * r0; o0.y = vv0.y * r0; o0.z = vv0.z * r0; o0.w = vv0.w * r0;
    o1.x = vv1.x * r1; o1.y = vv1.y * r1; o1.z = vv1.z * r1; o1.w = vv1.w * r1;
    *(float4*)(out + off0) = o0;
    *(float4*)(out + off1) = o1;
}

extern "C" void kernel_launch(void* const* d_in, const int* in_sizes, int n_in,
                              void* d_out, int out_size, void* d_ws, size_t ws_size,
                              hipStream_t stream) {
    const float* q = (const float*)d_in[0];
    const float* k = (const float*)d_in[1];
    const float* v = (const float*)d_in[2];
    float* out = (float*)d_out;
    float* ws  = (float*)d_ws;            // needs NBH*CC*DD*4 = 1 MB

    scan_kernel<<<NBH, 1024, 0, stream>>>(k, ws);                       // 16 blocks
    linattn_kernel<<<BB * HH * CC, 64, 0, stream>>>(q, k, v, ws, out);  // 4096 blocks
}

// Round 7
// 81.281 us; speedup vs baseline: 1.1605x; 1.1605x over previous
//
#include <hip/hip_runtime.h>

// Problem constants (B,T,H,D,M) = (2, 2048, 8, 64, 64), fp32 in/out.
#define BB 2
#define TT 2048
#define HH 8
#define DD 64
#define CC 256           // chunks over T
#define TC (TT / CC)     // 8 timesteps per chunk (= 4 segs x 2 iters)
#define STRIDE (HH * DD) // 512 floats between consecutive timesteps
#define NBH (BB * HH)    // 16
#define NG 16            // 16-chunk groups per (b,h)
#define GS_OFF ((size_t)NBH * CC * DD)  // float offset of group sums in ws

__device__ __forceinline__ float feat(float x) {
    // elu(x) + 1 = x+1 (x>0) else exp(x)
    return x > 0.f ? x + 1.f : __expf(x);
}

__device__ __forceinline__ void feat4(float4& a) {
    a.x = feat(a.x); a.y = feat(a.y); a.z = feat(a.z); a.w = feat(a.w);
}

// Sum the 4 seg groups' values into every lane (butterfly over lanes ^16, ^32).
__device__ __forceinline__ void xorred4(float4& a) {
    a.x += __shfl_xor(a.x, 16, 64); a.y += __shfl_xor(a.y, 16, 64);
    a.z += __shfl_xor(a.z, 16, 64); a.w += __shfl_xor(a.w, 16, 64);
    a.x += __shfl_xor(a.x, 32, 64); a.y += __shfl_xor(a.y, 32, 64);
    a.z += __shfl_xor(a.z, 32, 64); a.w += __shfl_xor(a.w, 32, 64);
}

// Lane map: g = lane&15 -> d-group (d = 4g..4g+3), seg = lane>>4 -> timestep
// within group-of-4. One wave float4-load = 4 timesteps x 64 d = 1 KB.

// Kernel 1: one block per (b,h,group-of-16-chunks) = 256 blocks x 1024 threads
// = 4096 waves (16 waves/CU -- as wide as the round-0 chunk_sums kernel).
// Wave w computes the chunk sum of chunk c = g16*16+w (identical per-wave work
// to round-0's k1), then one LDS exchange yields the EXCLUSIVE prefix within
// the group (written per chunk) and the group total (written by wave 15).
__global__ void __launch_bounds__(1024)
group_scan_kernel(const float* __restrict__ k, float* __restrict__ ws) {
    const int blk  = blockIdx.x;              // bh*NG + g16
    const int g16  = blk & (NG - 1);
    const int bh   = blk >> 4;
    const int w    = threadIdx.x >> 6;        // wave id = chunk within group
    const int lane = threadIdx.x & 63;
    const int g    = lane & 15;
    const int seg  = lane >> 4;
    const int b    = bh >> 3, h = bh & 7;
    const int c    = g16 * 16 + w;            // global chunk id

    const size_t off0 = (((size_t)b * TT + c * TC + seg) * HH + h) * DD + g * 4;
    float4 k0 = *(const float4*)(k + off0);
    float4 k1 = *(const float4*)(k + off0 + (size_t)4 * STRIDE);
    feat4(k0); feat4(k1);

    float4 s;
    s.x = k0.x + k1.x; s.y = k0.y + k1.y;
    s.z = k0.z + k1.z; s.w = k0.w + k1.w;
    xorred4(s);                  // all lanes hold this chunk's sum for their quad

    __shared__ float tot[16][DD];
    if (seg == 0)
        *(float4*)(&tot[w][g * 4]) = s;
    __syncthreads();

    // exclusive prefix within the group: sum tot[w2 < w], seg-strided (<=4 each)
    float4 ex = make_float4(0.f, 0.f, 0.f, 0.f);
    for (int w2 = seg; w2 < w; w2 += 4) {
        const float4 t = *(const float4*)(&tot[w2][g * 4]);
        ex.x += t.x; ex.y += t.y; ex.z += t.z; ex.w += t.w;
    }
    xorred4(ex);                 // all lanes: full exclusive-in-group prefix

    float* chunkE = ws;          // [NBH][CC][DD] exclusive-in-group prefixes
    float* groupS = ws + GS_OFF; // [NBH][NG][DD] group totals
    if (seg == 0) {
        *(float4*)(chunkE + ((size_t)bh * CC + c) * DD + g * 4) = ex;
        if (w == 15) {           // group total = excl of last chunk + its sum
            float4 gt;
            gt.x = ex.x + s.x; gt.y = ex.y + s.y;
            gt.z = ex.z + s.z; gt.w = ex.w + s.w;
            *(float4*)(groupS + ((size_t)bh * NG + g16) * DD + g * 4) = gt;
        }
    }
}

// Kernel 2: main (round-0 compute core). One wave per (b,h,c) chunk; carry =
// (<=4 seg-strided group-total loads + xorred4) + 1 exclusive-prefix load.
__global__ void __launch_bounds__(64)
linattn_kernel(const float* __restrict__ q, const float* __restrict__ k,
               const float* __restrict__ v, const float* __restrict__ ws,
               float* __restrict__ out) {
    const int idx  = blockIdx.x;
    const int c    = idx & (CC - 1);
    const int h    = (idx >> 8) & (HH - 1);
    const int b    = idx >> 11;
    const int bh   = idx >> 8;
    const int lane = threadIdx.x;
    const int g    = lane & 15;
    const int seg  = lane >> 4;

    // lane's timesteps: t0 = c*TC + seg (iter 0), t0+4 (iter 1); d = 4g..4g+3
    const size_t off0 = (((size_t)b * TT + c * TC + seg) * HH + h) * DD + g * 4;
    const size_t off1 = off0 + (size_t)4 * STRIDE;

    float4 kf0 = *(const float4*)(k + off0);
    float4 kf1 = *(const float4*)(k + off1);
    float4 qf0 = *(const float4*)(q + off0);
    float4 qf1 = *(const float4*)(q + off1);
    const float4 vv0 = *(const float4*)(v + off0);
    const float4 vv1 = *(const float4*)(v + off1);

    // ---- carry: full groups before c's group (L2-resident, seg-strided),
    // plus the in-group exclusive prefix (single load, full per-d value).
    const float* chunkE = ws;
    const float* groupS = ws + GS_OFF;
    float4 carry = make_float4(0.f, 0.f, 0.f, 0.f);
    const int ngp = c >> 4;
    const float* gsb = groupS + ((size_t)bh * NG) * DD + g * 4;
    for (int gp = seg; gp < ngp; gp += 4) {
        const float4 t = *(const float4*)(gsb + (size_t)gp * DD);
        carry.x += t.x; carry.y += t.y; carry.z += t.z; carry.w += t.w;
    }
    xorred4(carry);
    {
        const float4 e = *(const float4*)(chunkE + (size_t)idx * DD + g * 4);
        carry.x += e.x; carry.y += e.y; carry.z += e.z; carry.w += e.w;
    }

    feat4(kf0); feat4(kf1); feat4(qf0); feat4(qf1);

    // ---- time cumsum per d: seg-inclusive scans of kf0/kf1 (Hillis-Steele o=16,32)
    float4 i0 = kf0, i1 = kf1;
    {
        float u;
        u = __shfl_up(i0.x, 16, 64); if (seg >= 1) i0.x += u;
        u = __shfl_up(i0.y, 16, 64); if (seg >= 1) i0.y += u;
        u = __shfl_up(i0.z, 16, 64); if (seg >= 1) i0.z += u;
        u = __shfl_up(i0.w, 16, 64); if (seg >= 1) i0.w += u;
        u = __shfl_up(i1.x, 16, 64); if (seg >= 1) i1.x += u;
        u = __shfl_up(i1.y, 16, 64); if (seg >= 1) i1.y += u;
        u = __shfl_up(i1.z, 16, 64); if (seg >= 1) i1.z += u;
        u = __shfl_up(i1.w, 16, 64); if (seg >= 1) i1.w += u;
        u = __shfl_up(i0.x, 32, 64); if (seg >= 2) i0.x += u;
        u = __shfl_up(i0.y, 32, 64); if (seg >= 2) i0.y += u;
        u = __shfl_up(i0.z, 32, 64); if (seg >= 2) i0.z += u;
        u = __shfl_up(i0.w, 32, 64); if (seg >= 2) i0.w += u;
        u = __shfl_up(i1.x, 32, 64); if (seg >= 2) i1.x += u;
        u = __shfl_up(i1.y, 32, 64); if (seg >= 2) i1.y += u;
        u = __shfl_up(i1.z, 32, 64); if (seg >= 2) i1.z += u;
        u = __shfl_up(i1.w, 32, 64); if (seg >= 2) i1.w += u;
    }
    // S0[d] = chunk-first-half total = i0 at seg=3 (lane 48+g), broadcast
    float4 S0;
    S0.x = __shfl(i0.x, 48 + g, 64);
    S0.y = __shfl(i0.y, 48 + g, 64);
    S0.z = __shfl(i0.z, 48 + g, 64);
    S0.w = __shfl(i0.w, 48 + g, 64);

    float4 run0, run1;   // inclusive time-cumsum of feat(k) per d
    run0.x = carry.x + i0.x; run0.y = carry.y + i0.y;
    run0.z = carry.z + i0.z; run0.w = carry.w + i0.w;
    run1.x = carry.x + S0.x + i1.x; run1.y = carry.y + S0.y + i1.y;
    run1.z = carry.z + S0.z + i1.z; run1.w = carry.w + S0.w + i1.w;

    // ---- d-prefix (inclusive over d) per timestep: in-lane prefix + group scan
    float4 p0, p1;
    p0.x = kf0.x; p0.y = p0.x + kf0.y; p0.z = p0.y + kf0.z; p0.w = p0.z + kf0.w;
    p1.x = kf1.x; p1.y = p1.x + kf1.y; p1.z = p1.y + kf1.z; p1.w = p1.z + kf1.w;
    float c0 = p0.w, c1 = p1.w;
    #pragma unroll
    for (int o = 1; o <= 8; o <<= 1) {
        float u0 = __shfl_up(c0, o, 16);
        float u1 = __shfl_up(c1, o, 16);
        if (g >= o) { c0 += u0; c1 += u1; }
    }
    const float e0 = c0 - p0.w;   // exclusive d-prefix entering this lane
    const float e1 = c1 - p1.w;

    // ---- reductions over d: s1 = qf.(d-prefix), s2 = qf.run (per timestep)
    const float sq0 = qf0.x + qf0.y + qf0.z + qf0.w;
    const float sq1 = qf1.x + qf1.y + qf1.z + qf1.w;
    float s1_0 = qf0.x * p0.x + qf0.y * p0.y + qf0.z * p0.z + qf0.w * p0.w + e0 * sq0;
    float s2_0 = qf0.x * run0.x + qf0.y * run0.y + qf0.z * run0.z + qf0.w * run0.w;
    float s1_1 = qf1.x * p1.x + qf1.y * p1.y + qf1.z * p1.z + qf1.w * p1.w + e1 * sq1;
    float s2_1 = qf1.x * run1.x + qf1.y * run1.y + qf1.z * run1.z + qf1.w * run1.w;
    #pragma unroll
    for (int o = 1; o <= 8; o <<= 1) {
        s1_0 += __shfl_xor(s1_0, o, 64);
        s2_0 += __shfl_xor(s2_0, o, 64);
        s1_1 += __shfl_xor(s1_1, o, 64);
        s2_1 += __shfl_xor(s2_1, o, 64);
    }

    const float r0 = s1_0 * __builtin_amdgcn_rcpf(s2_0);
    const float r1 = s1_1 * __builtin_amdgcn_rcpf(s2_1);
    float4 o0, o1;
    o0.x = vv0.x * r0; o0.y = vv0.y * r0; o0.z = vv0.z * r0; o0.w = vv0.w * r0;
    o1.x = vv1.x * r1; o1.y = vv1.y * r1; o1.z = vv1.z * r1; o1.w = vv1.w * r1;
    *(float4*)(out + off0) = o0;
    *(float4*)(out + off1) = o1;
}

extern "C" void kernel_launch(void* const* d_in, const int* in_sizes, int n_in,
                              void* d_out, int out_size, void* d_ws, size_t ws_size,
                              hipStream_t stream) {
    const float* q = (const float*)d_in[0];
    const float* k = (const float*)d_in[1];
    const float* v = (const float*)d_in[2];
    float* out = (float*)d_out;
    float* ws  = (float*)d_ws;            // needs NBH*CC*DD + NBH*NG*DD floats ≈ 1.06 MB

    group_scan_kernel<<<NBH * NG, 1024, 0, stream>>>(k, ws);           // 256 blocks, 4096 waves
    linattn_kernel<<<BB * HH * CC, 64, 0, stream>>>(q, k, v, ws, out); // 4096 blocks
}

// Round 8
// 80.186 us; speedup vs baseline: 1.1763x; 1.0137x over previous
//
#include <hip/hip_runtime.h>

// Problem constants (B,T,H,D,M) = (2, 2048, 8, 64, 64), fp32 in/out.
#define BB 2
#define TT 2048
#define HH 8
#define DD 64
#define CC 256           // chunks over T
#define TC (TT / CC)     // 8 timesteps per chunk (= 4 segs x 2 iters)
#define STRIDE (HH * DD) // 512 floats between consecutive timesteps
#define NBH (BB * HH)    // 16
#define PW (CC / 16)     // 16 chunks per wave in prefix_kernel

__device__ __forceinline__ float feat(float x) {
    // elu(x) + 1 = x+1 (x>0) else exp(x)
    return x > 0.f ? x + 1.f : __expf(x);
}

__device__ __forceinline__ void feat4(float4& a) {
    a.x = feat(a.x); a.y = feat(a.y); a.z = feat(a.z); a.w = feat(a.w);
}

// Sum the 4 seg groups' values into every lane (butterfly over lanes ^16, ^32).
__device__ __forceinline__ void xorred4(float4& a) {
    a.x += __shfl_xor(a.x, 16, 64); a.y += __shfl_xor(a.y, 16, 64);
    a.z += __shfl_xor(a.z, 16, 64); a.w += __shfl_xor(a.w, 16, 64);
    a.x += __shfl_xor(a.x, 32, 64); a.y += __shfl_xor(a.y, 32, 64);
    a.z += __shfl_xor(a.z, 32, 64); a.w += __shfl_xor(a.w, 32, 64);
}

// Lane map: g = lane&15 -> d-group (d = 4g..4g+3), seg = lane>>4 -> timestep
// within group-of-4. One wave float4-load = 4 timesteps x 64 d = 1 KB.
// Round-8 change vs round-0: 4 waves per 256-thread block (8192 -> 2064 total
// workgroups), per-wave code identical.

// Kernel 1: per (b,h,c) chunk sums of feat(k) over time. One wave per chunk,
// 4 chunks per block.
__global__ void __launch_bounds__(256)
chunk_sums_kernel(const float* __restrict__ k, float* __restrict__ ws) {
    const int idx  = blockIdx.x * 4 + (threadIdx.x >> 6);  // (b*H + h)*CC + c
    const int c    = idx & (CC - 1);
    const int h    = (idx >> 8) & (HH - 1);
    const int b    = idx >> 11;
    const int lane = threadIdx.x & 63;
    const int g    = lane & 15;
    const int seg  = lane >> 4;

    const size_t off0 = (((size_t)b * TT + c * TC + seg) * HH + h) * DD + g * 4;
    const float4 k0 = *(const float4*)(k + off0);
    const float4 k1 = *(const float4*)(k + off0 + (size_t)4 * STRIDE);

    float4 s;
    s.x = feat(k0.x) + feat(k1.x);
    s.y = feat(k0.y) + feat(k1.y);
    s.z = feat(k0.z) + feat(k1.z);
    s.w = feat(k0.w) + feat(k1.w);

    xorred4(s);   // reduce over the 4 segments

    if (seg == 0)
        *(float4*)(ws + (size_t)idx * DD + g * 4) = s;
}

// Kernel 2 (verified): in-place ws chunk sums -> EXCLUSIVE prefix over c.
__global__ void __launch_bounds__(1024)
prefix_kernel(float* __restrict__ ws) {
    const int bh   = blockIdx.x;              // 0..15
    const int lane = threadIdx.x & 63;        // d
    const int w    = threadIdx.x >> 6;        // wave id 0..15

    size_t base = ((size_t)bh * CC + w * PW) * DD + lane;

    float val[PW];
    #pragma unroll
    for (int i = 0; i < PW; ++i) val[i] = ws[base + (size_t)i * DD];

    float run = 0.f, excl[PW];
    #pragma unroll
    for (int i = 0; i < PW; ++i) { excl[i] = run; run += val[i]; }

    __shared__ float tot[16][DD];
    tot[w][lane] = run;
    __syncthreads();

    float carry = 0.f;
    for (int w2 = 0; w2 < w; ++w2) carry += tot[w2][lane];

    #pragma unroll
    for (int i = 0; i < PW; ++i) ws[base + (size_t)i * DD] = excl[i] + carry;
}

// Kernel 3: main. One wave per (b,h,c) chunk, 4 chunks per block.
__global__ void __launch_bounds__(256)
linattn_kernel(const float* __restrict__ q, const float* __restrict__ k,
               const float* __restrict__ v, const float* __restrict__ ws,
               float* __restrict__ out) {
    const int idx  = blockIdx.x * 4 + (threadIdx.x >> 6);
    const int c    = idx & (CC - 1);
    const int h    = (idx >> 8) & (HH - 1);
    const int b    = idx >> 11;
    const int lane = threadIdx.x & 63;
    const int g    = lane & 15;
    const int seg  = lane >> 4;

    // lane's timesteps: t0 = c*TC + seg (iter 0), t0+4 (iter 1); d = 4g..4g+3
    const size_t off0 = (((size_t)b * TT + c * TC + seg) * HH + h) * DD + g * 4;
    const size_t off1 = off0 + (size_t)4 * STRIDE;

    float4 kf0 = *(const float4*)(k + off0);
    float4 kf1 = *(const float4*)(k + off1);
    float4 qf0 = *(const float4*)(q + off0);
    float4 qf1 = *(const float4*)(q + off1);
    const float4 vv0 = *(const float4*)(v + off0);
    const float4 vv1 = *(const float4*)(v + off1);
    const float4 carry = *(const float4*)(ws + (size_t)idx * DD + g * 4); // excl prefix per d

    feat4(kf0); feat4(kf1); feat4(qf0); feat4(qf1);

    // ---- time cumsum per d: seg-inclusive scans of kf0/kf1 (Hillis-Steele o=16,32)
    float4 i0 = kf0, i1 = kf1;
    {
        float u;
        u = __shfl_up(i0.x, 16, 64); if (seg >= 1) i0.x += u;
        u = __shfl_up(i0.y, 16, 64); if (seg >= 1) i0.y += u;
        u = __shfl_up(i0.z, 16, 64); if (seg >= 1) i0.z += u;
        u = __shfl_up(i0.w, 16, 64); if (seg >= 1) i0.w += u;
        u = __shfl_up(i1.x, 16, 64); if (seg >= 1) i1.x += u;
        u = __shfl_up(i1.y, 16, 64); if (seg >= 1) i1.y += u;
        u = __shfl_up(i1.z, 16, 64); if (seg >= 1) i1.z += u;
        u = __shfl_up(i1.w, 16, 64); if (seg >= 1) i1.w += u;
        u = __shfl_up(i0.x, 32, 64); if (seg >= 2) i0.x += u;
        u = __shfl_up(i0.y, 32, 64); if (seg >= 2) i0.y += u;
        u = __shfl_up(i0.z, 32, 64); if (seg >= 2) i0.z += u;
        u = __shfl_up(i0.w, 32, 64); if (seg >= 2) i0.w += u;
        u = __shfl_up(i1.x, 32, 64); if (seg >= 2) i1.x += u;
        u = __shfl_up(i1.y, 32, 64); if (seg >= 2) i1.y += u;
        u = __shfl_up(i1.z, 32, 64); if (seg >= 2) i1.z += u;
        u = __shfl_up(i1.w, 32, 64); if (seg >= 2) i1.w += u;
    }
    // S0[d] = chunk-first-half total = i0 at seg=3 (lane 48+g), broadcast
    float4 S0;
    S0.x = __shfl(i0.x, 48 + g, 64);
    S0.y = __shfl(i0.y, 48 + g, 64);
    S0.z = __shfl(i0.z, 48 + g, 64);
    S0.w = __shfl(i0.w, 48 + g, 64);

    float4 run0, run1;   // inclusive time-cumsum of feat(k) per d
    run0.x = carry.x + i0.x; run0.y = carry.y + i0.y;
    run0.z = carry.z + i0.z; run0.w = carry.w + i0.w;
    run1.x = carry.x + S0.x + i1.x; run1.y = carry.y + S0.y + i1.y;
    run1.z = carry.z + S0.z + i1.z; run1.w = carry.w + S0.w + i1.w;

    // ---- d-prefix (inclusive over d) per timestep: in-lane prefix + group scan
    float4 p0, p1;
    p0.x = kf0.x; p0.y = p0.x + kf0.y; p0.z = p0.y + kf0.z; p0.w = p0.z + kf0.w;
    p1.x = kf1.x; p1.y = p1.x + kf1.y; p1.z = p1.y + kf1.z; p1.w = p1.z + kf1.w;
    float c0 = p0.w, c1 = p1.w;
    #pragma unroll
    for (int o = 1; o <= 8; o <<= 1) {
        float u0 = __shfl_up(c0, o, 16);
        float u1 = __shfl_up(c1, o, 16);
        if (g >= o) { c0 += u0; c1 += u1; }
    }
    const float e0 = c0 - p0.w;   // exclusive d-prefix entering this lane
    const float e1 = c1 - p1.w;

    // ---- reductions over d: s1 = qf.(d-prefix), s2 = qf.run (per timestep)
    const float sq0 = qf0.x + qf0.y + qf0.z + qf0.w;
    const float sq1 = qf1.x + qf1.y + qf1.z + qf1.w;
    float s1_0 = qf0.x * p0.x + qf0.y * p0.y + qf0.z * p0.z + qf0.w * p0.w + e0 * sq0;
    float s2_0 = qf0.x * run0.x + qf0.y * run0.y + qf0.z * run0.z + qf0.w * run0.w;
    float s1_1 = qf1.x * p1.x + qf1.y * p1.y + qf1.z * p1.z + qf1.w * p1.w + e1 * sq1;
    float s2_1 = qf1.x * run1.x + qf1.y * run1.y + qf1.z * run1.z + qf1.w * run1.w;
    #pragma unroll
    for (int o = 1; o <= 8; o <<= 1) {
        s1_0 += __shfl_xor(s1_0, o, 64);
        s2_0 += __shfl_xor(s2_0, o, 64);
        s1_1 += __shfl_xor(s1_1, o, 64);
        s2_1 += __shfl_xor(s2_1, o, 64);
    }

    const float r0 = s1_0 * __builtin_amdgcn_rcpf(s2_0);
    const float r1 = s1_1 * __builtin_amdgcn_rcpf(s2_1);
    float4 o0, o1;
    o0.x = vv0.x * r0; o0.y = vv0.y * r0; o0.z = vv0.z * r0; o0.w = vv0.w * r0;
    o1.x = vv1.x * r1; o1.y = vv1.y * r1; o1.z = vv1.z * r1; o1.w = vv1.w * r1;
    *(float4*)(out + off0) = o0;
    *(float4*)(out + off1) = o1;
}

extern "C" void kernel_launch(void* const* d_in, const int* in_sizes, int n_in,
                              void* d_out, int out_size, void* d_ws, size_t ws_size,
                              hipStream_t stream) {
    const float* q = (const float*)d_in[0];
    const float* k = (const float*)d_in[1];
    const float* v = (const float*)d_in[2];
    float* out = (float*)d_out;
    float* ws  = (float*)d_ws;            // needs B*H*CC*DD*4 = 1 MB

    const int nblk = (BB * HH * CC) / 4;  // 1024 blocks of 256 threads
    chunk_sums_kernel<<<nblk, 256, 0, stream>>>(k, ws);
    prefix_kernel<<<NBH, 1024, 0, stream>>>(ws);
    linattn_kernel<<<nblk, 256, 0, stream>>>(q, k, v, ws, out);
}